// Round 13
// baseline (271.584 us; speedup 1.0000x reference)
//
#include <hip/hip_runtime.h>

// GraphSAGE link predictor. f16 row-major intermediates, 2-pass CSR bucket,
// MFMA node GEMMs (h1+g fused), swapped-MFMA edge MLP (low-VGPR).
// Pipeline:
//  kA: x16 = f16(x) + deg hist (fused)
//  scan (cbinit fused into scan3) ; k_coarse ; k_fine_sort (CSR srcs)
//  agg16 = f16(segsum(x16[src]))            (gather, 8 lanes/row, unroll 8)
//  k_h1g: h1 = (agg*inv)@Wl1 + x16@Wr1 + bl1 ; g = h1@Wl2 (LDS-fused, MFMA)
//  agg16 = f16(segsum(g[src]))              (gather)
//  h2 = h1@Wr2 + agg*inv + bl2              (MFMA, f16 out)
//  out[e] = relu((h2[s]*h2[d])@W1+b1)@W2+b2 (MFMA swapped D=[hid x edge])

typedef _Float16 f16x8 __attribute__((ext_vector_type(8)));
typedef float f32x4 __attribute__((ext_vector_type(4)));

union H4 { _Float16 h[4]; uint2 u; };
union H8 { _Float16 h[8]; uint4 u; };

__device__ inline uint2 pack4(float4 v) {
  H4 p;
  p.h[0] = (_Float16)v.x; p.h[1] = (_Float16)v.y;
  p.h[2] = (_Float16)v.z; p.h[3] = (_Float16)v.w;
  return p.u;
}

// ---------------- kA: f32->f16 convert + deg histogram ----------------
__global__ void kA_convert_hist(const float* __restrict__ x, _Float16* __restrict__ x16,
                                const int* __restrict__ dst, int* __restrict__ deg,
                                int n4, int E) {
  int t = blockIdx.x * blockDim.x + threadIdx.x;
  if (t < n4) {
    float4 v = ((const float4*)x)[t];
    ((uint2*)x16)[t] = pack4(v);
  }
  if (t < E) atomicAdd(&deg[dst[t]], 1);
}

// ---------------- scans ----------------
__global__ void k_scan1(const int* __restrict__ deg, int* __restrict__ ex,
                        int* __restrict__ bsum, int N) {
  __shared__ int sm[256];
  int t = threadIdx.x, i = blockIdx.x * 256 + t;
  int v = (i < N) ? deg[i] : 0;
  sm[t] = v;
  __syncthreads();
  for (int s = 1; s < 256; s <<= 1) {
    int a = (t >= s) ? sm[t - s] : 0;
    __syncthreads();
    sm[t] += a;
    __syncthreads();
  }
  if (i < N) ex[i] = sm[t] - v;
  if (t == 255) bsum[blockIdx.x] = sm[255];
}

__global__ void k_scan2(int* __restrict__ bsum, int nb) {
  __shared__ int sm[1024];
  int t = threadIdx.x;
  int v = (t < nb) ? bsum[t] : 0;
  sm[t] = v;
  __syncthreads();
  for (int s = 1; s < 1024; s <<= 1) {
    int a = (t >= s) ? sm[t - s] : 0;
    __syncthreads();
    sm[t] += a;
    __syncthreads();
  }
  if (t < nb) bsum[t] = sm[t] - v;
}

// scan3 + cbinit fused
__global__ void k_scan3(const int* __restrict__ bsum, int* __restrict__ row,
                        const int* __restrict__ ex, int* __restrict__ cbcursor,
                        int N, int E) {
  int i = blockIdx.x * blockDim.x + threadIdx.x;
  if (i < N) {
    int v = ex[i] + bsum[i >> 8];
    row[i] = v;
    if ((i & 255) == 0) cbcursor[i >> 8] = v;
  }
  if (i == 0) row[N] = E;
}

// ---------------- pass A: bucket edges by dst>>8 into packed u64 streams ----------
__global__ __launch_bounds__(256) void k_coarse(
    const int* __restrict__ src, const int* __restrict__ dst,
    int* __restrict__ cbcursor, unsigned long long* __restrict__ ep, int E) {
  __shared__ int lh[512];
  const int t = threadIdx.x;
  const int chunk = (E + gridDim.x - 1) / gridDim.x;
  const int e0 = blockIdx.x * chunk;
  const int e1 = min(e0 + chunk, E);
  lh[t] = 0; lh[t + 256] = 0;
  __syncthreads();
  for (int e = e0 + t; e < e1; e += 256)
    atomicAdd(&lh[dst[e] >> 8], 1);
  __syncthreads();
  {
    int c0 = lh[t], c1 = lh[t + 256];
    int b0 = c0 ? atomicAdd(&cbcursor[t], c0) : 0;
    int b1 = c1 ? atomicAdd(&cbcursor[t + 256], c1) : 0;
    __syncthreads();
    lh[t] = b0; lh[t + 256] = b1;
  }
  __syncthreads();
  for (int e = e0 + t; e < e1; e += 256) {
    int d = dst[e];
    int pos = atomicAdd(&lh[d >> 8], 1);
    ep[pos] = ((unsigned long long)d << 32) | (unsigned)src[e];
  }
}

// ---------------- pass B: per-bucket LDS count-sort -> coalesced srcs ----------
#define FS_CAP 4608
__global__ __launch_bounds__(256) void k_fine_sort(
    const unsigned long long* __restrict__ ep, const int* __restrict__ row,
    int* __restrict__ srcs, int N, int E) {
  __shared__ int cnt[256];
  __shared__ int cur[256];
  __shared__ int sm[256];
  __shared__ int stage[FS_CAP];
  const int b = blockIdx.x;
  const int t = threadIdx.x;
  const int n0 = b << 8;
  const int n1 = min(n0 + 256, N);
  const int beg = row[n0];
  const int end = row[n1];
  const int M = end - beg;

  cnt[t] = 0;
  __syncthreads();
  for (int i = beg + t; i < end; i += 256) {
    int loc = (int)(ep[i] >> 32) & 255;
    atomicAdd(&cnt[loc], 1);
  }
  __syncthreads();
  int v = cnt[t];
  sm[t] = v;
  __syncthreads();
  for (int s = 1; s < 256; s <<= 1) {
    int a = (t >= s) ? sm[t - s] : 0;
    __syncthreads();
    sm[t] += a;
    __syncthreads();
  }
  cur[t] = sm[t] - v;
  __syncthreads();
  for (int i = beg + t; i < end; i += 256) {
    unsigned long long p = ep[i];
    int loc = (int)(p >> 32) & 255;
    int pos = atomicAdd(&cur[loc], 1);
    if (pos < FS_CAP) stage[pos] = (int)(unsigned)p;
    else srcs[beg + pos] = (int)(unsigned)p;   // statistically never
  }
  __syncthreads();
  const int m = min(M, FS_CAP);
  for (int i = t; i < m; i += 256) srcs[beg + i] = stage[i];
}

// ---------------- aggregation: 8 lanes/row (16B each), unroll 8, f16 out --------
__global__ __launch_bounds__(256) void k_gather16(
    const _Float16* __restrict__ feat, const int* __restrict__ row,
    const int* __restrict__ srcs, _Float16* __restrict__ agg, int N) {
  int tid = blockIdx.x * blockDim.x + threadIdx.x;
  int node = tid >> 3, slot = tid & 7;
  if (node >= N) return;
  int beg = row[node], end = row[node + 1];
  float acc[8];
#pragma unroll
  for (int i = 0; i < 8; i++) acc[i] = 0.f;
  int k = beg;
  for (; k + 7 < end; k += 8) {
    H8 r[8];
#pragma unroll
    for (int j = 0; j < 8; j++)
      r[j].u = *(const uint4*)(feat + (size_t)srcs[k + j] * 64 + slot * 8);
#pragma unroll
    for (int i = 0; i < 8; i++)
      acc[i] += (((float)r[0].h[i] + (float)r[1].h[i]) +
                 ((float)r[2].h[i] + (float)r[3].h[i])) +
                (((float)r[4].h[i] + (float)r[5].h[i]) +
                 ((float)r[6].h[i] + (float)r[7].h[i]));
  }
  for (; k + 1 < end; k += 2) {
    H8 a, b;
    a.u = *(const uint4*)(feat + (size_t)srcs[k] * 64 + slot * 8);
    b.u = *(const uint4*)(feat + (size_t)srcs[k + 1] * 64 + slot * 8);
#pragma unroll
    for (int i = 0; i < 8; i++) acc[i] += (float)a.h[i] + (float)b.h[i];
  }
  if (k < end) {
    H8 a; a.u = *(const uint4*)(feat + (size_t)srcs[k] * 64 + slot * 8);
#pragma unroll
    for (int i = 0; i < 8; i++) acc[i] += (float)a.h[i];
  }
  H8 o;
#pragma unroll
  for (int i = 0; i < 8; i++) o.h[i] = (_Float16)acc[i];
  *(uint4*)(agg + (size_t)node * 64 + slot * 8) = o.u;
}

// ---------------- fused h1 + g MFMA kernel ----------------
__global__ __launch_bounds__(256) void k_h1g_mfma(
    const _Float16* __restrict__ agg, const _Float16* __restrict__ x16,
    const float* __restrict__ Wl1, const float* __restrict__ Wr1,
    const float* __restrict__ bl1, const float* __restrict__ Wl2,
    const int* __restrict__ deg,
    _Float16* __restrict__ h1o, _Float16* __restrict__ g16, int N) {
  __shared__ _Float16 ostage[4][16][136];
  const int w = threadIdx.x >> 6;
  const int l = threadIdx.x & 63;
  const int col = l & 15;
  const int kb8 = (l >> 4) * 8;
  const int nb = blockIdx.x * 64 + w * 16;
  const int nodeA = min(nb + col, N - 1);

  f16x8 wf[8][2];
#pragma unroll
  for (int tt = 0; tt < 8; tt++)
#pragma unroll
    for (int s = 0; s < 2; s++) {
      f16x8 v;
#pragma unroll
      for (int e = 0; e < 8; e++)
        v[e] = (_Float16)Wl1[(size_t)(s * 32 + kb8 + e) * 128 + tt * 16 + col];
      wf[tt][s] = v;
    }
  f16x8 af[2];
#pragma unroll
  for (int s = 0; s < 2; s++)
    af[s] = *(const f16x8*)(agg + (size_t)nodeA * 64 + s * 32 + kb8);

  f32x4 acc[8];
#pragma unroll
  for (int tt = 0; tt < 8; tt++) {
    f32x4 a = {0.f, 0.f, 0.f, 0.f};
#pragma unroll
    for (int s = 0; s < 2; s++)
      a = __builtin_amdgcn_mfma_f32_16x16x32_f16(af[s], wf[tt][s], a, 0, 0, 0);
    acc[tt] = a;
  }

  float inv[4];
#pragma unroll
  for (int reg = 0; reg < 4; reg++) {
    int nd = min(nb + (l >> 4) * 4 + reg, N - 1);
    inv[reg] = 1.0f / fmaxf((float)deg[nd], 1.0f);
  }
#pragma unroll
  for (int tt = 0; tt < 8; tt++)
#pragma unroll
    for (int reg = 0; reg < 4; reg++) acc[tt][reg] *= inv[reg];

  f16x8 wfb[8][2];
#pragma unroll
  for (int tt = 0; tt < 8; tt++)
#pragma unroll
    for (int s = 0; s < 2; s++) {
      f16x8 v;
#pragma unroll
      for (int e = 0; e < 8; e++)
        v[e] = (_Float16)Wr1[(size_t)(s * 32 + kb8 + e) * 128 + tt * 16 + col];
      wfb[tt][s] = v;
    }
#pragma unroll
  for (int s = 0; s < 2; s++)
    af[s] = *(const f16x8*)(x16 + (size_t)nodeA * 64 + s * 32 + kb8);
#pragma unroll
  for (int tt = 0; tt < 8; tt++)
#pragma unroll
    for (int s = 0; s < 2; s++)
      acc[tt] = __builtin_amdgcn_mfma_f32_16x16x32_f16(af[s], wfb[tt][s], acc[tt], 0, 0, 0);
#pragma unroll
  for (int tt = 0; tt < 8; tt++) {
    float bl = bl1[tt * 16 + col];
#pragma unroll
    for (int reg = 0; reg < 4; reg++) acc[tt][reg] += bl;
  }

#pragma unroll
  for (int tt = 0; tt < 8; tt++)
#pragma unroll
    for (int reg = 0; reg < 4; reg++)
      ostage[w][(l >> 4) * 4 + reg][tt * 16 + col] = (_Float16)acc[tt][reg];
  __syncthreads();
#pragma unroll
  for (int i = 0; i < 4; i++) {
    int idx = i * 64 + l;
    int r = idx >> 4, q = idx & 15;
    int gn = nb + r;
    if (gn < N)
      *(uint4*)(h1o + (size_t)gn * 128 + q * 8) = *(const uint4*)(&ostage[w][r][q * 8]);
  }

  // g = h1 @ Wl2 (A-frags from own wave's LDS partition)
  f16x8 wf2[4][4];
#pragma unroll
  for (int tt = 0; tt < 4; tt++)
#pragma unroll
    for (int s = 0; s < 4; s++) {
      f16x8 v;
#pragma unroll
      for (int e = 0; e < 8; e++)
        v[e] = (_Float16)Wl2[(size_t)(s * 32 + kb8 + e) * 64 + tt * 16 + col];
      wf2[tt][s] = v;
    }
  f16x8 af2[4];
#pragma unroll
  for (int s = 0; s < 4; s++)
    af2[s] = *(const f16x8*)(&ostage[w][col][s * 32 + kb8]);

  f32x4 acc2[4];
#pragma unroll
  for (int tt = 0; tt < 4; tt++) {
    f32x4 a = {0.f, 0.f, 0.f, 0.f};
#pragma unroll
    for (int s = 0; s < 4; s++)
      a = __builtin_amdgcn_mfma_f32_16x16x32_f16(af2[s], wf2[tt][s], a, 0, 0, 0);
    acc2[tt] = a;
  }

#pragma unroll
  for (int tt = 0; tt < 4; tt++)
#pragma unroll
    for (int reg = 0; reg < 4; reg++)
      ostage[w][(l >> 4) * 4 + reg][tt * 16 + col] = (_Float16)acc2[tt][reg];
  __syncthreads();
#pragma unroll
  for (int i = 0; i < 2; i++) {
    int idx = i * 64 + l;
    int r = idx >> 3, q = idx & 7;
    int gn = nb + r;
    if (gn < N)
      *(uint4*)(g16 + (size_t)gn * 64 + q * 8) = *(const uint4*)(&ostage[w][r][q * 8]);
  }
}

// ---------------- MFMA node GEMM (h2) ----------------
__global__ __launch_bounds__(256) void k_h2_mfma(
    const _Float16* __restrict__ A, const float* __restrict__ W,
    const float* __restrict__ bias, const _Float16* __restrict__ add64,
    const int* __restrict__ deg, _Float16* __restrict__ outp, int N) {
  constexpr int KS = 4;
  constexpr int TT = 4;
  __shared__ _Float16 ostage[4][16][72];

  const int w = threadIdx.x >> 6;
  const int l = threadIdx.x & 63;
  const int col = l & 15;
  const int kb8 = (l >> 4) * 8;
  const int nb = blockIdx.x * 64 + w * 16;
  const int nodeA = min(nb + col, N - 1);

  f16x8 wf[TT][KS];
#pragma unroll
  for (int tt = 0; tt < TT; tt++)
#pragma unroll
    for (int s = 0; s < KS; s++) {
      f16x8 v;
#pragma unroll
      for (int e = 0; e < 8; e++)
        v[e] = (_Float16)W[(size_t)(s * 32 + kb8 + e) * 64 + tt * 16 + col];
      wf[tt][s] = v;
    }
  f16x8 af[KS];
#pragma unroll
  for (int s = 0; s < KS; s++)
    af[s] = *(const f16x8*)(A + (size_t)nodeA * 128 + s * 32 + kb8);

  f32x4 acc[TT];
#pragma unroll
  for (int tt = 0; tt < TT; tt++) {
    f32x4 a = {0.f, 0.f, 0.f, 0.f};
#pragma unroll
    for (int s = 0; s < KS; s++)
      a = __builtin_amdgcn_mfma_f32_16x16x32_f16(af[s], wf[tt][s], a, 0, 0, 0);
    acc[tt] = a;
  }

  float inv[4];
  int ndc[4];
#pragma unroll
  for (int reg = 0; reg < 4; reg++) {
    ndc[reg] = min(nb + (l >> 4) * 4 + reg, N - 1);
    inv[reg] = 1.0f / fmaxf((float)deg[ndc[reg]], 1.0f);
  }
#pragma unroll
  for (int tt = 0; tt < TT; tt++) {
    float bl = bias[tt * 16 + col];
#pragma unroll
    for (int reg = 0; reg < 4; reg++) {
      float ad = (float)add64[(size_t)ndc[reg] * 64 + tt * 16 + col];
      acc[tt][reg] += ad * inv[reg] + bl;
    }
  }

#pragma unroll
  for (int tt = 0; tt < TT; tt++)
#pragma unroll
    for (int reg = 0; reg < 4; reg++)
      ostage[w][(l >> 4) * 4 + reg][tt * 16 + col] = (_Float16)acc[tt][reg];
  __syncthreads();
#pragma unroll
  for (int i = 0; i < 2; i++) {
    int idx = i * 64 + l;
    int r = idx >> 3, q = idx & 7;
    int gn = nb + r;
    if (gn < N)
      *(uint4*)(outp + (size_t)gn * 64 + q * 8) = *(const uint4*)(&ostage[w][r][q * 8]);
  }
}

// ---------------- edge MLP: swapped MFMA, low-VGPR (b1/W2 loaded in-loop) --------
__global__ __launch_bounds__(256) void k_edge_mfma(
    const _Float16* __restrict__ h2, const int* __restrict__ src,
    const int* __restrict__ dst,
    const float* __restrict__ W1, const float* __restrict__ W2,
    const float* __restrict__ b1, const float* __restrict__ b2,
    float* __restrict__ out, int E) {
  const int gtid = blockIdx.x * blockDim.x + threadIdx.x;
  const int wave = gtid >> 6;
  const int nwaves = (gridDim.x * blockDim.x) >> 6;
  const int l = threadIdx.x & 63;
  const int col = l & 15;
  const int kb = (l >> 4) * 8;
  const int hb = (l >> 4) * 4;
  const int ngroups = (E + 15) / 16;
  const int gpw = (ngroups + nwaves - 1) / nwaves;
  const int g0 = wave * gpw;
  const int g1 = min(g0 + gpw, ngroups);
  if (g0 >= ngroups) return;

  f16x8 afrag[8][2];
#pragma unroll
  for (int tt = 0; tt < 8; tt++)
#pragma unroll
    for (int s = 0; s < 2; s++) {
      f16x8 bf;
#pragma unroll
      for (int e = 0; e < 8; e++)
        bf[e] = (_Float16)W1[(size_t)(s * 32 + kb + e) * 128 + tt * 16 + col];
      afrag[tt][s] = bf;
    }
  const float b2v = b2[0];

  auto ldrows = [&](int g, f16x8& a0, f16x8& a1) {
    int pos = g * 16 + col;
    if (pos >= E) pos = E - 1;
    int sp = src[pos], dp = dst[pos];
    f16x8 as0 = *(const f16x8*)(h2 + (size_t)sp * 64 + kb);
    f16x8 ad0 = *(const f16x8*)(h2 + (size_t)dp * 64 + kb);
    f16x8 as1 = *(const f16x8*)(h2 + (size_t)sp * 64 + 32 + kb);
    f16x8 ad1 = *(const f16x8*)(h2 + (size_t)dp * 64 + 32 + kb);
    a0 = as0 * ad0;
    a1 = as1 * ad1;
  };

  auto compute = [&](int g, f16x8 a0, f16x8 a1) {
    float psum = 0.f;
#pragma unroll
    for (int tt = 0; tt < 8; tt++) {
      float4 c0t = *(const float4*)(b1 + tt * 16 + hb);   // L1-hot, loaded in-loop
      float4 w2t = *(const float4*)(W2 + tt * 16 + hb);
      f32x4 acc = {c0t.x, c0t.y, c0t.z, c0t.w};
      acc = __builtin_amdgcn_mfma_f32_16x16x32_f16(afrag[tt][0], a0, acc, 0, 0, 0);
      acc = __builtin_amdgcn_mfma_f32_16x16x32_f16(afrag[tt][1], a1, acc, 0, 0, 0);
      psum += fmaxf(acc[0], 0.f) * w2t.x + fmaxf(acc[1], 0.f) * w2t.y
            + fmaxf(acc[2], 0.f) * w2t.z + fmaxf(acc[3], 0.f) * w2t.w;
    }
    psum += __shfl_xor(psum, 16, 64);
    psum += __shfl_xor(psum, 32, 64);
    if (l < 16) {
      int epos = g * 16 + l;
      if (epos < E) out[epos] = psum + b2v;
    }
  };

  f16x8 a0, a1, na0, na1;
  ldrows(g0, a0, a1);
  for (int g = g0; g < g1; g++) {
    if (g + 1 < g1) ldrows(g + 1, na0, na1);
    compute(g, a0, a1);
    a0 = na0; a1 = na1;
  }
}

// ---------------- launch ----------------
extern "C" void kernel_launch(void* const* d_in, const int* in_sizes, int n_in,
                              void* d_out, int out_size, void* d_ws, size_t ws_size,
                              hipStream_t stream) {
  const float* x   = (const float*)d_in[0];
  const int*   ei  = (const int*)d_in[1];
  const float* Wl1 = (const float*)d_in[2];
  const float* bl1 = (const float*)d_in[3];
  const float* Wr1 = (const float*)d_in[4];
  const float* Wl2 = (const float*)d_in[5];
  const float* bl2 = (const float*)d_in[6];
  const float* Wr2 = (const float*)d_in[7];
  const float* W1  = (const float*)d_in[8];
  const float* b1  = (const float*)d_in[9];
  const float* W2  = (const float*)d_in[10];
  const float* b2  = (const float*)d_in[11];
  const int N = in_sizes[0] / 64;
  const int E = in_sizes[1] / 2;
  const int* src = ei;
  const int* dstp = ei + E;

  char* w = (char*)d_ws;
  size_t off = 0;
  auto alloc = [&](size_t bytes) -> void* {
    void* p = w + off;
    off = (off + bytes + 255) & ~(size_t)255;
    return p;
  };
  int*      deg      = (int*)alloc((size_t)N * 4);
  int*      row      = (int*)alloc((size_t)(N + 1) * 4);
  int*      ex       = (int*)alloc((size_t)N * 4);
  int*      bsum     = (int*)alloc(1024 * 4);
  int*      cbcursor = (int*)alloc(512 * 4);
  int*      srcs     = (int*)alloc((size_t)E * 4);
  unsigned long long* ep = (unsigned long long*)alloc((size_t)E * 8);
  _Float16* f16buf   = (_Float16*)alloc((size_t)N * 64 * 2);   // x16 -> g16 -> h2
  _Float16* agg16    = (_Float16*)alloc((size_t)N * 64 * 2);   // aggX -> aggG
  _Float16* h1_16    = (_Float16*)alloc((size_t)N * 128 * 2);

  const int ncb = (N + 255) >> 8;

  hipMemsetAsync(deg, 0, (size_t)N * 4, stream);
  int n4 = N * 16;
  int kag = (max(n4, E) + 255) / 256;
  kA_convert_hist<<<kag, 256, 0, stream>>>(x, f16buf, dstp, deg, n4, E);
  int nb = (N + 255) / 256;
  k_scan1<<<nb, 256, 0, stream>>>(deg, ex, bsum, N);
  k_scan2<<<1, 1024, 0, stream>>>(bsum, nb);
  k_scan3<<<nb, 256, 0, stream>>>(bsum, row, ex, cbcursor, N, E);
  k_coarse<<<512, 256, 0, stream>>>(src, dstp, cbcursor, ep, E);
  k_fine_sort<<<ncb, 256, 0, stream>>>(ep, row, srcs, N, E);

  int ngrid = (N + 63) / 64;
  int ggrid = (N * 8 + 255) / 256;
  k_gather16<<<ggrid, 256, 0, stream>>>(f16buf, row, srcs, agg16, N);
  k_h1g_mfma<<<ngrid, 256, 0, stream>>>(agg16, f16buf, Wl1, Wr1, bl1, Wl2, deg,
                                        h1_16, f16buf, N);
  k_gather16<<<ggrid, 256, 0, stream>>>(f16buf, row, srcs, agg16, N);
  k_h2_mfma<<<ngrid, 256, 0, stream>>>(h1_16, Wr2, bl2, agg16, deg, f16buf, N);
  k_edge_mfma<<<4096, 256, 0, stream>>>(f16buf, src, dstp, W1, W2, b1, b2,
                                        (float*)d_out, E);
}

// Round 14
// 268.612 us; speedup vs baseline: 1.0111x; 1.0111x over previous
//
#include <hip/hip_runtime.h>

// GraphSAGE link predictor. f16 row-major intermediates, 2-pass CSR bucket,
// MFMA node GEMMs (h1+g fused), swapped-MFMA edge MLP (W1 in LDS, high-occupancy).
// Pipeline:
//  kA: x16 = f16(x) + deg hist (fused)
//  scan (cbinit fused into scan3) ; k_coarse ; k_fine_sort (CSR srcs)
//  agg16 = f16(segsum(x16[src]))            (gather, 8 lanes/row, unroll 8)
//  k_h1g: h1 = (agg*inv)@Wl1 + x16@Wr1 + bl1 ; g = h1@Wl2 (LDS-fused, MFMA)
//  agg16 = f16(segsum(g[src]))              (gather)
//  h2 = h1@Wr2 + agg*inv + bl2              (MFMA, f16 out)
//  out[e] = relu((h2[s]*h2[d])@W1+b1)@W2+b2 (MFMA swapped, W1 frags from LDS)

typedef _Float16 f16x8 __attribute__((ext_vector_type(8)));
typedef float f32x4 __attribute__((ext_vector_type(4)));

union H4 { _Float16 h[4]; uint2 u; };
union H8 { _Float16 h[8]; uint4 u; };

__device__ inline uint2 pack4(float4 v) {
  H4 p;
  p.h[0] = (_Float16)v.x; p.h[1] = (_Float16)v.y;
  p.h[2] = (_Float16)v.z; p.h[3] = (_Float16)v.w;
  return p.u;
}

// ---------------- kA: f32->f16 convert + deg histogram ----------------
__global__ void kA_convert_hist(const float* __restrict__ x, _Float16* __restrict__ x16,
                                const int* __restrict__ dst, int* __restrict__ deg,
                                int n4, int E) {
  int t = blockIdx.x * blockDim.x + threadIdx.x;
  if (t < n4) {
    float4 v = ((const float4*)x)[t];
    ((uint2*)x16)[t] = pack4(v);
  }
  if (t < E) atomicAdd(&deg[dst[t]], 1);
}

// ---------------- scans ----------------
__global__ void k_scan1(const int* __restrict__ deg, int* __restrict__ ex,
                        int* __restrict__ bsum, int N) {
  __shared__ int sm[256];
  int t = threadIdx.x, i = blockIdx.x * 256 + t;
  int v = (i < N) ? deg[i] : 0;
  sm[t] = v;
  __syncthreads();
  for (int s = 1; s < 256; s <<= 1) {
    int a = (t >= s) ? sm[t - s] : 0;
    __syncthreads();
    sm[t] += a;
    __syncthreads();
  }
  if (i < N) ex[i] = sm[t] - v;
  if (t == 255) bsum[blockIdx.x] = sm[255];
}

__global__ void k_scan2(int* __restrict__ bsum, int nb) {
  __shared__ int sm[1024];
  int t = threadIdx.x;
  int v = (t < nb) ? bsum[t] : 0;
  sm[t] = v;
  __syncthreads();
  for (int s = 1; s < 1024; s <<= 1) {
    int a = (t >= s) ? sm[t - s] : 0;
    __syncthreads();
    sm[t] += a;
    __syncthreads();
  }
  if (t < nb) bsum[t] = sm[t] - v;
}

// scan3 + cbinit fused
__global__ void k_scan3(const int* __restrict__ bsum, int* __restrict__ row,
                        const int* __restrict__ ex, int* __restrict__ cbcursor,
                        int N, int E) {
  int i = blockIdx.x * blockDim.x + threadIdx.x;
  if (i < N) {
    int v = ex[i] + bsum[i >> 8];
    row[i] = v;
    if ((i & 255) == 0) cbcursor[i >> 8] = v;
  }
  if (i == 0) row[N] = E;
}

// ---------------- pass A: bucket edges by dst>>8 into packed u64 streams ----------
__global__ __launch_bounds__(256) void k_coarse(
    const int* __restrict__ src, const int* __restrict__ dst,
    int* __restrict__ cbcursor, unsigned long long* __restrict__ ep, int E) {
  __shared__ int lh[512];
  const int t = threadIdx.x;
  const int chunk = (E + gridDim.x - 1) / gridDim.x;
  const int e0 = blockIdx.x * chunk;
  const int e1 = min(e0 + chunk, E);
  lh[t] = 0; lh[t + 256] = 0;
  __syncthreads();
  for (int e = e0 + t; e < e1; e += 256)
    atomicAdd(&lh[dst[e] >> 8], 1);
  __syncthreads();
  {
    int c0 = lh[t], c1 = lh[t + 256];
    int b0 = c0 ? atomicAdd(&cbcursor[t], c0) : 0;
    int b1 = c1 ? atomicAdd(&cbcursor[t + 256], c1) : 0;
    __syncthreads();
    lh[t] = b0; lh[t + 256] = b1;
  }
  __syncthreads();
  for (int e = e0 + t; e < e1; e += 256) {
    int d = dst[e];
    int pos = atomicAdd(&lh[d >> 8], 1);
    ep[pos] = ((unsigned long long)d << 32) | (unsigned)src[e];
  }
}

// ---------------- pass B: per-bucket LDS count-sort -> coalesced srcs ----------
#define FS_CAP 4608
__global__ __launch_bounds__(256) void k_fine_sort(
    const unsigned long long* __restrict__ ep, const int* __restrict__ row,
    int* __restrict__ srcs, int N, int E) {
  __shared__ int cnt[256];
  __shared__ int cur[256];
  __shared__ int sm[256];
  __shared__ int stage[FS_CAP];
  const int b = blockIdx.x;
  const int t = threadIdx.x;
  const int n0 = b << 8;
  const int n1 = min(n0 + 256, N);
  const int beg = row[n0];
  const int end = row[n1];
  const int M = end - beg;

  cnt[t] = 0;
  __syncthreads();
  for (int i = beg + t; i < end; i += 256) {
    int loc = (int)(ep[i] >> 32) & 255;
    atomicAdd(&cnt[loc], 1);
  }
  __syncthreads();
  int v = cnt[t];
  sm[t] = v;
  __syncthreads();
  for (int s = 1; s < 256; s <<= 1) {
    int a = (t >= s) ? sm[t - s] : 0;
    __syncthreads();
    sm[t] += a;
    __syncthreads();
  }
  cur[t] = sm[t] - v;
  __syncthreads();
  for (int i = beg + t; i < end; i += 256) {
    unsigned long long p = ep[i];
    int loc = (int)(p >> 32) & 255;
    int pos = atomicAdd(&cur[loc], 1);
    if (pos < FS_CAP) stage[pos] = (int)(unsigned)p;
    else srcs[beg + pos] = (int)(unsigned)p;   // statistically never
  }
  __syncthreads();
  const int m = min(M, FS_CAP);
  for (int i = t; i < m; i += 256) srcs[beg + i] = stage[i];
}

// ---------------- aggregation: 8 lanes/row (16B each), unroll 8, f16 out --------
__global__ __launch_bounds__(256) void k_gather16(
    const _Float16* __restrict__ feat, const int* __restrict__ row,
    const int* __restrict__ srcs, _Float16* __restrict__ agg, int N) {
  int tid = blockIdx.x * blockDim.x + threadIdx.x;
  int node = tid >> 3, slot = tid & 7;
  if (node >= N) return;
  int beg = row[node], end = row[node + 1];
  float acc[8];
#pragma unroll
  for (int i = 0; i < 8; i++) acc[i] = 0.f;
  int k = beg;
  for (; k + 7 < end; k += 8) {
    H8 r[8];
#pragma unroll
    for (int j = 0; j < 8; j++)
      r[j].u = *(const uint4*)(feat + (size_t)srcs[k + j] * 64 + slot * 8);
#pragma unroll
    for (int i = 0; i < 8; i++)
      acc[i] += (((float)r[0].h[i] + (float)r[1].h[i]) +
                 ((float)r[2].h[i] + (float)r[3].h[i])) +
                (((float)r[4].h[i] + (float)r[5].h[i]) +
                 ((float)r[6].h[i] + (float)r[7].h[i]));
  }
  for (; k + 1 < end; k += 2) {
    H8 a, b;
    a.u = *(const uint4*)(feat + (size_t)srcs[k] * 64 + slot * 8);
    b.u = *(const uint4*)(feat + (size_t)srcs[k + 1] * 64 + slot * 8);
#pragma unroll
    for (int i = 0; i < 8; i++) acc[i] += (float)a.h[i] + (float)b.h[i];
  }
  if (k < end) {
    H8 a; a.u = *(const uint4*)(feat + (size_t)srcs[k] * 64 + slot * 8);
#pragma unroll
    for (int i = 0; i < 8; i++) acc[i] += (float)a.h[i];
  }
  H8 o;
#pragma unroll
  for (int i = 0; i < 8; i++) o.h[i] = (_Float16)acc[i];
  *(uint4*)(agg + (size_t)node * 64 + slot * 8) = o.u;
}

// ---------------- fused h1 + g MFMA kernel ----------------
__global__ __launch_bounds__(256) void k_h1g_mfma(
    const _Float16* __restrict__ agg, const _Float16* __restrict__ x16,
    const float* __restrict__ Wl1, const float* __restrict__ Wr1,
    const float* __restrict__ bl1, const float* __restrict__ Wl2,
    const int* __restrict__ deg,
    _Float16* __restrict__ h1o, _Float16* __restrict__ g16, int N) {
  __shared__ _Float16 ostage[4][16][136];
  const int w = threadIdx.x >> 6;
  const int l = threadIdx.x & 63;
  const int col = l & 15;
  const int kb8 = (l >> 4) * 8;
  const int nb = blockIdx.x * 64 + w * 16;
  const int nodeA = min(nb + col, N - 1);

  f16x8 wf[8][2];
#pragma unroll
  for (int tt = 0; tt < 8; tt++)
#pragma unroll
    for (int s = 0; s < 2; s++) {
      f16x8 v;
#pragma unroll
      for (int e = 0; e < 8; e++)
        v[e] = (_Float16)Wl1[(size_t)(s * 32 + kb8 + e) * 128 + tt * 16 + col];
      wf[tt][s] = v;
    }
  f16x8 af[2];
#pragma unroll
  for (int s = 0; s < 2; s++)
    af[s] = *(const f16x8*)(agg + (size_t)nodeA * 64 + s * 32 + kb8);

  f32x4 acc[8];
#pragma unroll
  for (int tt = 0; tt < 8; tt++) {
    f32x4 a = {0.f, 0.f, 0.f, 0.f};
#pragma unroll
    for (int s = 0; s < 2; s++)
      a = __builtin_amdgcn_mfma_f32_16x16x32_f16(af[s], wf[tt][s], a, 0, 0, 0);
    acc[tt] = a;
  }

  float inv[4];
#pragma unroll
  for (int reg = 0; reg < 4; reg++) {
    int nd = min(nb + (l >> 4) * 4 + reg, N - 1);
    inv[reg] = 1.0f / fmaxf((float)deg[nd], 1.0f);
  }
#pragma unroll
  for (int tt = 0; tt < 8; tt++)
#pragma unroll
    for (int reg = 0; reg < 4; reg++) acc[tt][reg] *= inv[reg];

  f16x8 wfb[8][2];
#pragma unroll
  for (int tt = 0; tt < 8; tt++)
#pragma unroll
    for (int s = 0; s < 2; s++) {
      f16x8 v;
#pragma unroll
      for (int e = 0; e < 8; e++)
        v[e] = (_Float16)Wr1[(size_t)(s * 32 + kb8 + e) * 128 + tt * 16 + col];
      wfb[tt][s] = v;
    }
#pragma unroll
  for (int s = 0; s < 2; s++)
    af[s] = *(const f16x8*)(x16 + (size_t)nodeA * 64 + s * 32 + kb8);
#pragma unroll
  for (int tt = 0; tt < 8; tt++)
#pragma unroll
    for (int s = 0; s < 2; s++)
      acc[tt] = __builtin_amdgcn_mfma_f32_16x16x32_f16(af[s], wfb[tt][s], acc[tt], 0, 0, 0);
#pragma unroll
  for (int tt = 0; tt < 8; tt++) {
    float bl = bl1[tt * 16 + col];
#pragma unroll
    for (int reg = 0; reg < 4; reg++) acc[tt][reg] += bl;
  }

#pragma unroll
  for (int tt = 0; tt < 8; tt++)
#pragma unroll
    for (int reg = 0; reg < 4; reg++)
      ostage[w][(l >> 4) * 4 + reg][tt * 16 + col] = (_Float16)acc[tt][reg];
  __syncthreads();
#pragma unroll
  for (int i = 0; i < 4; i++) {
    int idx = i * 64 + l;
    int r = idx >> 4, q = idx & 15;
    int gn = nb + r;
    if (gn < N)
      *(uint4*)(h1o + (size_t)gn * 128 + q * 8) = *(const uint4*)(&ostage[w][r][q * 8]);
  }

  // g = h1 @ Wl2 (A-frags from own wave's LDS partition)
  f16x8 wf2[4][4];
#pragma unroll
  for (int tt = 0; tt < 4; tt++)
#pragma unroll
    for (int s = 0; s < 4; s++) {
      f16x8 v;
#pragma unroll
      for (int e = 0; e < 8; e++)
        v[e] = (_Float16)Wl2[(size_t)(s * 32 + kb8 + e) * 64 + tt * 16 + col];
      wf2[tt][s] = v;
    }
  f16x8 af2[4];
#pragma unroll
  for (int s = 0; s < 4; s++)
    af2[s] = *(const f16x8*)(&ostage[w][col][s * 32 + kb8]);

  f32x4 acc2[4];
#pragma unroll
  for (int tt = 0; tt < 4; tt++) {
    f32x4 a = {0.f, 0.f, 0.f, 0.f};
#pragma unroll
    for (int s = 0; s < 4; s++)
      a = __builtin_amdgcn_mfma_f32_16x16x32_f16(af2[s], wf2[tt][s], a, 0, 0, 0);
    acc2[tt] = a;
  }

#pragma unroll
  for (int tt = 0; tt < 4; tt++)
#pragma unroll
    for (int reg = 0; reg < 4; reg++)
      ostage[w][(l >> 4) * 4 + reg][tt * 16 + col] = (_Float16)acc2[tt][reg];
  __syncthreads();
#pragma unroll
  for (int i = 0; i < 2; i++) {
    int idx = i * 64 + l;
    int r = idx >> 3, q = idx & 7;
    int gn = nb + r;
    if (gn < N)
      *(uint4*)(g16 + (size_t)gn * 64 + q * 8) = *(const uint4*)(&ostage[w][r][q * 8]);
  }
}

// ---------------- MFMA node GEMM (h2) ----------------
__global__ __launch_bounds__(256) void k_h2_mfma(
    const _Float16* __restrict__ A, const float* __restrict__ W,
    const float* __restrict__ bias, const _Float16* __restrict__ add64,
    const int* __restrict__ deg, _Float16* __restrict__ outp, int N) {
  constexpr int KS = 4;
  constexpr int TT = 4;
  __shared__ _Float16 ostage[4][16][72];

  const int w = threadIdx.x >> 6;
  const int l = threadIdx.x & 63;
  const int col = l & 15;
  const int kb8 = (l >> 4) * 8;
  const int nb = blockIdx.x * 64 + w * 16;
  const int nodeA = min(nb + col, N - 1);

  f16x8 wf[TT][KS];
#pragma unroll
  for (int tt = 0; tt < TT; tt++)
#pragma unroll
    for (int s = 0; s < KS; s++) {
      f16x8 v;
#pragma unroll
      for (int e = 0; e < 8; e++)
        v[e] = (_Float16)W[(size_t)(s * 32 + kb8 + e) * 64 + tt * 16 + col];
      wf[tt][s] = v;
    }
  f16x8 af[KS];
#pragma unroll
  for (int s = 0; s < KS; s++)
    af[s] = *(const f16x8*)(A + (size_t)nodeA * 128 + s * 32 + kb8);

  f32x4 acc[TT];
#pragma unroll
  for (int tt = 0; tt < TT; tt++) {
    f32x4 a = {0.f, 0.f, 0.f, 0.f};
#pragma unroll
    for (int s = 0; s < KS; s++)
      a = __builtin_amdgcn_mfma_f32_16x16x32_f16(af[s], wf[tt][s], a, 0, 0, 0);
    acc[tt] = a;
  }

  float inv[4];
  int ndc[4];
#pragma unroll
  for (int reg = 0; reg < 4; reg++) {
    ndc[reg] = min(nb + (l >> 4) * 4 + reg, N - 1);
    inv[reg] = 1.0f / fmaxf((float)deg[ndc[reg]], 1.0f);
  }
#pragma unroll
  for (int tt = 0; tt < TT; tt++) {
    float bl = bias[tt * 16 + col];
#pragma unroll
    for (int reg = 0; reg < 4; reg++) {
      float ad = (float)add64[(size_t)ndc[reg] * 64 + tt * 16 + col];
      acc[tt][reg] += ad * inv[reg] + bl;
    }
  }

#pragma unroll
  for (int tt = 0; tt < TT; tt++)
#pragma unroll
    for (int reg = 0; reg < 4; reg++)
      ostage[w][(l >> 4) * 4 + reg][tt * 16 + col] = (_Float16)acc[tt][reg];
  __syncthreads();
#pragma unroll
  for (int i = 0; i < 2; i++) {
    int idx = i * 64 + l;
    int r = idx >> 3, q = idx & 7;
    int gn = nb + r;
    if (gn < N)
      *(uint4*)(outp + (size_t)gn * 64 + q * 8) = *(const uint4*)(&ostage[w][r][q * 8]);
  }
}

// ---------------- edge MLP: swapped MFMA, W1 frags in LDS (low VGPR) ------------
// w1lds[j][k] f16, row stride 72 (144B, 16B-aligned, 2-way-free banks on b128).
__global__ __launch_bounds__(256) void k_edge_mfma(
    const _Float16* __restrict__ h2, const int* __restrict__ src,
    const int* __restrict__ dst,
    const float* __restrict__ W1, const float* __restrict__ W2,
    const float* __restrict__ b1, const float* __restrict__ b2,
    float* __restrict__ out, int E) {
  __shared__ _Float16 w1lds[128][72];
  // stage W1^T: W1 is [64 k][128 j] row-major -> w1lds[j][k]
  for (int idx = threadIdx.x; idx < 8192; idx += 256) {
    int k = idx >> 7, j = idx & 127;
    w1lds[j][k] = (_Float16)W1[idx];
  }
  __syncthreads();

  const int gtid = blockIdx.x * blockDim.x + threadIdx.x;
  const int wave = gtid >> 6;
  const int nwaves = (gridDim.x * blockDim.x) >> 6;
  const int l = threadIdx.x & 63;
  const int col = l & 15;
  const int kb = (l >> 4) * 8;
  const int hb = (l >> 4) * 4;
  const int ngroups = (E + 15) / 16;
  const int gpw = (ngroups + nwaves - 1) / nwaves;
  const int g0 = wave * gpw;
  const int g1 = min(g0 + gpw, ngroups);
  if (g0 >= ngroups) return;

  const float b2v = b2[0];

  auto ldrows = [&](int g, f16x8& a0, f16x8& a1) {
    int pos = g * 16 + col;
    if (pos >= E) pos = E - 1;
    int sp = src[pos], dp = dst[pos];
    f16x8 as0 = *(const f16x8*)(h2 + (size_t)sp * 64 + kb);
    f16x8 ad0 = *(const f16x8*)(h2 + (size_t)dp * 64 + kb);
    f16x8 as1 = *(const f16x8*)(h2 + (size_t)sp * 64 + 32 + kb);
    f16x8 ad1 = *(const f16x8*)(h2 + (size_t)dp * 64 + 32 + kb);
    a0 = as0 * ad0;
    a1 = as1 * ad1;
  };

  auto compute = [&](int g, f16x8 a0, f16x8 a1) {
    float psum = 0.f;
#pragma unroll
    for (int tt = 0; tt < 8; tt++) {
      float4 c0t = *(const float4*)(b1 + tt * 16 + hb);   // L1-hot
      float4 w2t = *(const float4*)(W2 + tt * 16 + hb);
      f16x8 wa0 = *(const f16x8*)(&w1lds[tt * 16 + col][kb]);
      f16x8 wa1 = *(const f16x8*)(&w1lds[tt * 16 + col][32 + kb]);
      f32x4 acc = {c0t.x, c0t.y, c0t.z, c0t.w};
      acc = __builtin_amdgcn_mfma_f32_16x16x32_f16(wa0, a0, acc, 0, 0, 0);
      acc = __builtin_amdgcn_mfma_f32_16x16x32_f16(wa1, a1, acc, 0, 0, 0);
      psum += fmaxf(acc[0], 0.f) * w2t.x + fmaxf(acc[1], 0.f) * w2t.y
            + fmaxf(acc[2], 0.f) * w2t.z + fmaxf(acc[3], 0.f) * w2t.w;
    }
    psum += __shfl_xor(psum, 16, 64);
    psum += __shfl_xor(psum, 32, 64);
    if (l < 16) {
      int epos = g * 16 + l;
      if (epos < E) out[epos] = psum + b2v;
    }
  };

  f16x8 a0, a1, na0, na1;
  ldrows(g0, a0, a1);
  for (int g = g0; g < g1; g++) {
    if (g + 1 < g1) ldrows(g + 1, na0, na1);
    compute(g, a0, a1);
    a0 = na0; a1 = na1;
  }
}

// ---------------- launch ----------------
extern "C" void kernel_launch(void* const* d_in, const int* in_sizes, int n_in,
                              void* d_out, int out_size, void* d_ws, size_t ws_size,
                              hipStream_t stream) {
  const float* x   = (const float*)d_in[0];
  const int*   ei  = (const int*)d_in[1];
  const float* Wl1 = (const float*)d_in[2];
  const float* bl1 = (const float*)d_in[3];
  const float* Wr1 = (const float*)d_in[4];
  const float* Wl2 = (const float*)d_in[5];
  const float* bl2 = (const float*)d_in[6];
  const float* Wr2 = (const float*)d_in[7];
  const float* W1  = (const float*)d_in[8];
  const float* b1  = (const float*)d_in[9];
  const float* W2  = (const float*)d_in[10];
  const float* b2  = (const float*)d_in[11];
  const int N = in_sizes[0] / 64;
  const int E = in_sizes[1] / 2;
  const int* src = ei;
  const int* dstp = ei + E;

  char* w = (char*)d_ws;
  size_t off = 0;
  auto alloc = [&](size_t bytes) -> void* {
    void* p = w + off;
    off = (off + bytes + 255) & ~(size_t)255;
    return p;
  };
  int*      deg      = (int*)alloc((size_t)N * 4);
  int*      row      = (int*)alloc((size_t)(N + 1) * 4);
  int*      ex       = (int*)alloc((size_t)N * 4);
  int*      bsum     = (int*)alloc(1024 * 4);
  int*      cbcursor = (int*)alloc(512 * 4);
  int*      srcs     = (int*)alloc((size_t)E * 4);
  unsigned long long* ep = (unsigned long long*)alloc((size_t)E * 8);
  _Float16* f16buf   = (_Float16*)alloc((size_t)N * 64 * 2);   // x16 -> g16 -> h2
  _Float16* agg16    = (_Float16*)alloc((size_t)N * 64 * 2);   // aggX -> aggG
  _Float16* h1_16    = (_Float16*)alloc((size_t)N * 128 * 2);

  const int ncb = (N + 255) >> 8;

  hipMemsetAsync(deg, 0, (size_t)N * 4, stream);
  int n4 = N * 16;
  int kag = (max(n4, E) + 255) / 256;
  kA_convert_hist<<<kag, 256, 0, stream>>>(x, f16buf, dstp, deg, n4, E);
  int nb = (N + 255) / 256;
  k_scan1<<<nb, 256, 0, stream>>>(deg, ex, bsum, N);
  k_scan2<<<1, 1024, 0, stream>>>(bsum, nb);
  k_scan3<<<nb, 256, 0, stream>>>(bsum, row, ex, cbcursor, N, E);
  k_coarse<<<256, 256, 0, stream>>>(src, dstp, cbcursor, ep, E);
  k_fine_sort<<<ncb, 256, 0, stream>>>(ep, row, srcs, N, E);

  int ngrid = (N + 63) / 64;
  int ggrid = (N * 8 + 255) / 256;
  k_gather16<<<ggrid, 256, 0, stream>>>(f16buf, row, srcs, agg16, N);
  k_h1g_mfma<<<ngrid, 256, 0, stream>>>(agg16, f16buf, Wl1, Wr1, bl1, Wl2, deg,
                                        h1_16, f16buf, N);
  k_gather16<<<ggrid, 256, 0, stream>>>(f16buf, row, srcs, agg16, N);
  k_h2_mfma<<<ngrid, 256, 0, stream>>>(h1_16, Wr2, bl2, agg16, deg, f16buf, N);
  k_edge_mfma<<<4096, 256, 0, stream>>>(f16buf, src, dstp, W1, W2, b1, b2,
                                        (float*)d_out, E);
}